// Round 1
// baseline (1043.364 us; speedup 1.0000x reference)
//
#include <hip/hip_runtime.h>

#define T 512
#define B 2
#define NH 16
#define FD 16
#define HD 64
#define DFEAT 153

// triu_indices(16,1) pairs, row-major (i from 0, j>i)
__constant__ unsigned char c_iu[120] = {
0,0,0,0,0,0,0,0,0,0,0,0,0,0,0,
1,1,1,1,1,1,1,1,1,1,1,1,1,1,
2,2,2,2,2,2,2,2,2,2,2,2,2,
3,3,3,3,3,3,3,3,3,3,3,3,
4,4,4,4,4,4,4,4,4,4,4,
5,5,5,5,5,5,5,5,5,5,
6,6,6,6,6,6,6,6,6,
7,7,7,7,7,7,7,7,
8,8,8,8,8,8,8,
9,9,9,9,9,9,
10,10,10,10,10,
11,11,11,11,
12,12,12,
13,13,
14};
__constant__ unsigned char c_ju[120] = {
1,2,3,4,5,6,7,8,9,10,11,12,13,14,15,
2,3,4,5,6,7,8,9,10,11,12,13,14,15,
3,4,5,6,7,8,9,10,11,12,13,14,15,
4,5,6,7,8,9,10,11,12,13,14,15,
5,6,7,8,9,10,11,12,13,14,15,
6,7,8,9,10,11,12,13,14,15,
7,8,9,10,11,12,13,14,15,
8,9,10,11,12,13,14,15,
9,10,11,12,13,14,15,
10,11,12,13,14,15,
11,12,13,14,15,
12,13,14,15,
13,14,15,
14,15,
15};

// C[M,N] = A[M,K] @ B[N,K]^T  (all row-major). M%64==0, N%64==0, K%16==0.
__global__ __launch_bounds__(256)
void gemm_abt(const float* __restrict__ A, const float* __restrict__ Bm,
              float* __restrict__ C, int M, int N, int K) {
    __shared__ float As[16][65];
    __shared__ float Bs[16][65];
    const int bm = blockIdx.y * 64, bn = blockIdx.x * 64;
    const int tid = threadIdx.x;
    const int tx = tid & 15, ty = tid >> 4;
    const int r  = tid >> 2, c4 = (tid & 3) << 2;
    float acc[4][4] = {};
    for (int k0 = 0; k0 < K; k0 += 16) {
        float4 av = *(const float4*)(A  + (size_t)(bm + r) * K + k0 + c4);
        float4 bv = *(const float4*)(Bm + (size_t)(bn + r) * K + k0 + c4);
        As[c4+0][r] = av.x; As[c4+1][r] = av.y; As[c4+2][r] = av.z; As[c4+3][r] = av.w;
        Bs[c4+0][r] = bv.x; Bs[c4+1][r] = bv.y; Bs[c4+2][r] = bv.z; Bs[c4+3][r] = bv.w;
        __syncthreads();
        #pragma unroll
        for (int kk = 0; kk < 16; ++kk) {
            float a[4], b[4];
            #pragma unroll
            for (int i = 0; i < 4; ++i) a[i] = As[kk][ty*4+i];
            #pragma unroll
            for (int j = 0; j < 4; ++j) b[j] = Bs[kk][tx*4+j];
            #pragma unroll
            for (int i = 0; i < 4; ++i)
                #pragma unroll
                for (int j = 0; j < 4; ++j) acc[i][j] += a[i]*b[j];
        }
        __syncthreads();
    }
    #pragma unroll
    for (int i = 0; i < 4; ++i) {
        float4 o = make_float4(acc[i][0], acc[i][1], acc[i][2], acc[i][3]);
        *(float4*)(C + (size_t)(bm + ty*4 + i) * N + bn + tx*4) = o;
    }
}

// One block per (b,h). 256 threads: d = tid>>2 (0..63), g = tid&3 (D stride-4 slice).
// State kv[d][D] and z[D] held in registers (39 entries each, D padded to 156).
__global__ __launch_bounds__(256)
void scan_attn(const float* __restrict__ Q, const float* __restrict__ Kf,
               const float* __restrict__ V, float* __restrict__ Y) {
    const int bh = blockIdx.x;            // 0..31
    const int b = bh >> 4, h = bh & 15;
    const int tid = threadIdx.x;
    const int g = tid & 3, d = tid >> 2;
    __shared__ float sqf[2][156], skf[2][156];
    if (tid >= 153 && tid < 156) {
        sqf[0][tid] = 0.f; sqf[1][tid] = 0.f;
        skf[0][tid] = 0.f; skf[1][tid] = 0.f;
    }
    float st[39], zst[39];
    #pragma unroll
    for (int j = 0; j < 39; ++j) { st[j] = 0.f; zst[j] = 0.f; }
    __syncthreads();
    for (int t = 0; t < T; ++t) {
        const int bt = b * T + t;
        const int buf = t & 1;
        if (tid < DFEAT) {
            const float* qrow = Q  + (size_t)bt*(NH*FD) + h*FD;
            const float* krow = Kf + (size_t)bt*(NH*FD) + h*FD;
            float qv, kv;
            if (tid == 0)       { qv = 1.f; kv = 1.f; }
            else if (tid < 17)  { qv = qrow[tid-1]*0.5f; kv = krow[tid-1]*0.5f; }
            else if (tid < 33)  { float a = qrow[tid-17], c = krow[tid-17];
                                  qv = a*a*0.17677669529663687f;
                                  kv = c*c*0.17677669529663687f; }
            else                { int p = tid - 33; int ii = c_iu[p], jj = c_ju[p];
                                  qv = qrow[ii]*qrow[jj]*0.25f;
                                  kv = krow[ii]*krow[jj]*0.25f; }
            sqf[buf][tid] = qv; skf[buf][tid] = kv;
        }
        __syncthreads();
        const float vd = V[(size_t)bt*(NH*HD) + h*HD + d];
        const float* qb = sqf[buf];
        const float* kb = skf[buf];
        float yy = 0.f, dd = 0.f;
        #pragma unroll
        for (int j = 0; j < 39; ++j) {
            const int D = g + (j << 2);
            float kD = kb[D], qD = qb[D];
            st[j]  += kD * vd;  yy += qD * st[j];
            zst[j] += kD;       dd += qD * zst[j];
        }
        yy += __shfl_xor(yy, 1); yy += __shfl_xor(yy, 2);
        dd += __shfl_xor(dd, 1); dd += __shfl_xor(dd, 2);
        if (g == 0) Y[(size_t)bt*(NH*HD) + h*HD + d] = yy / (dd + 1e-12f);
    }
}

extern "C" void kernel_launch(void* const* d_in, const int* in_sizes, int n_in,
                              void* d_out, int out_size, void* d_ws, size_t ws_size,
                              hipStream_t stream) {
    const float* hs = (const float*)d_in[0];
    const float* Wq = (const float*)d_in[1];
    const float* Wk = (const float*)d_in[2];
    const float* Wv = (const float*)d_in[3];
    const float* Wo = (const float*)d_in[4];
    float* out = (float*)d_out;

    float* Q  = (float*)d_ws;                       // B*T*256
    float* Kp = Q  + (size_t)B*T*NH*FD;             // B*T*256
    float* V  = Kp + (size_t)B*T*NH*FD;             // B*T*1024
    float* Y  = V  + (size_t)B*T*NH*HD;             // B*T*1024

    const int M = B * T;   // 1024
    dim3 blk(256);
    gemm_abt<<<dim3((NH*FD)/64, M/64), blk, 0, stream>>>(hs, Wq, Q,  M, NH*FD, 1024);
    gemm_abt<<<dim3((NH*FD)/64, M/64), blk, 0, stream>>>(hs, Wk, Kp, M, NH*FD, 1024);
    gemm_abt<<<dim3(1024/64,    M/64), blk, 0, stream>>>(hs, Wv, V,  M, 1024, 1024);
    scan_attn<<<dim3(B*NH), blk, 0, stream>>>(Q, Kp, V, Y);
    gemm_abt<<<dim3(1024/64,    M/64), blk, 0, stream>>>(Y, Wo, out, M, 1024, 1024);
}

// Round 2
// 424.114 us; speedup vs baseline: 2.4601x; 2.4601x over previous
//
#include <hip/hip_runtime.h>

#define T 512
#define B 2
#define NH 16
#define FD 16
#define HD 64
#define DFEAT 153
#define DP 160      // padded feature dim (zeros in [153,160))
#define CH 64       // chunk length
#define NC 8        // T/CH

__constant__ unsigned char c_iu[120] = {
0,0,0,0,0,0,0,0,0,0,0,0,0,0,0,
1,1,1,1,1,1,1,1,1,1,1,1,1,1,
2,2,2,2,2,2,2,2,2,2,2,2,2,
3,3,3,3,3,3,3,3,3,3,3,3,
4,4,4,4,4,4,4,4,4,4,4,
5,5,5,5,5,5,5,5,5,5,
6,6,6,6,6,6,6,6,6,
7,7,7,7,7,7,7,7,
8,8,8,8,8,8,8,
9,9,9,9,9,9,
10,10,10,10,10,
11,11,11,11,
12,12,12,
13,13,
14};
__constant__ unsigned char c_ju[120] = {
1,2,3,4,5,6,7,8,9,10,11,12,13,14,15,
2,3,4,5,6,7,8,9,10,11,12,13,14,15,
3,4,5,6,7,8,9,10,11,12,13,14,15,
4,5,6,7,8,9,10,11,12,13,14,15,
5,6,7,8,9,10,11,12,13,14,15,
6,7,8,9,10,11,12,13,14,15,
7,8,9,10,11,12,13,14,15,
8,9,10,11,12,13,14,15,
9,10,11,12,13,14,15,
10,11,12,13,14,15,
11,12,13,14,15,
12,13,14,15,
13,14,15,
14,15,
15};

// C[M,N] = A[M,K] @ B[N,K]^T (row-major). M%64==0, N%64==0, K%16==0.
__global__ __launch_bounds__(256)
void gemm_abt(const float* __restrict__ A, const float* __restrict__ Bm,
              float* __restrict__ C, int M, int N, int K) {
    __shared__ float As[16][65];
    __shared__ float Bs[16][65];
    const int bm = blockIdx.y * 64, bn = blockIdx.x * 64;
    const int tid = threadIdx.x;
    const int tx = tid & 15, ty = tid >> 4;
    const int r  = tid >> 2, c4 = (tid & 3) << 2;
    float acc[4][4] = {};
    for (int k0 = 0; k0 < K; k0 += 16) {
        float4 av = *(const float4*)(A  + (size_t)(bm + r) * K + k0 + c4);
        float4 bv = *(const float4*)(Bm + (size_t)(bn + r) * K + k0 + c4);
        As[c4+0][r] = av.x; As[c4+1][r] = av.y; As[c4+2][r] = av.z; As[c4+3][r] = av.w;
        Bs[c4+0][r] = bv.x; Bs[c4+1][r] = bv.y; Bs[c4+2][r] = bv.z; Bs[c4+3][r] = bv.w;
        __syncthreads();
        #pragma unroll
        for (int kk = 0; kk < 16; ++kk) {
            float a[4], b[4];
            #pragma unroll
            for (int i = 0; i < 4; ++i) a[i] = As[kk][ty*4+i];
            #pragma unroll
            for (int j = 0; j < 4; ++j) b[j] = Bs[kk][tx*4+j];
            #pragma unroll
            for (int i = 0; i < 4; ++i)
                #pragma unroll
                for (int j = 0; j < 4; ++j) acc[i][j] += a[i]*b[j];
        }
        __syncthreads();
    }
    #pragma unroll
    for (int i = 0; i < 4; ++i) {
        float4 o = make_float4(acc[i][0], acc[i][1], acc[i][2], acc[i][3]);
        *(float4*)(C + (size_t)(bm + ty*4 + i) * N + bn + tx*4) = o;
    }
}

// Q,K: [B*T][256] -> Qf,Kf: [bh][t][DP] feature-mapped, pad zeroed.
__global__ __launch_bounds__(256)
void featurize(const float* __restrict__ Q, const float* __restrict__ K,
               float* __restrict__ Qf, float* __restrict__ Kf) {
    const int bt = blockIdx.x;            // 0..B*T-1
    const int b = bt >> 9, t = bt & 511;
    const int tid = threadIdx.x;
    __shared__ float sq[256], sk[256];
    sq[tid] = Q[(size_t)bt*256 + tid];
    sk[tid] = K[(size_t)bt*256 + tid];
    __syncthreads();
    const int h = tid >> 4, sl = tid & 15;   // head, 10-feature slice
    const float* q = sq + h*16;
    const float* k = sk + h*16;
    const size_t obase = (((size_t)(b*NH + h))*T + t)*DP + sl*10;
    float* oq = Qf + obase;
    float* ok = Kf + obase;
    #pragma unroll
    for (int m = 0; m < 10; ++m) {
        const int D = sl*10 + m;
        float fq, fk;
        if (D == 0)        { fq = 1.f; fk = 1.f; }
        else if (D < 17)   { fq = q[D-1]*0.5f; fk = k[D-1]*0.5f; }
        else if (D < 33)   { float a = q[D-17], c = k[D-17];
                             fq = a*a*0.17677669529663687f;
                             fk = c*c*0.17677669529663687f; }
        else if (D < 153)  { int p = D-33; int ii = c_iu[p], jj = c_ju[p];
                             fq = q[ii]*q[jj]*0.25f;
                             fk = k[ii]*k[jj]*0.25f; }
        else               { fq = 0.f; fk = 0.f; }
        oq[m] = fq; ok[m] = fk;
    }
}

// Per (bh, chunk): S[d][D] = sum_t V[t][d]*Kf[t][D]; z[D] = sum_t Kf[t][D]
__global__ __launch_bounds__(256)
void chunk_state(const float* __restrict__ Kf, const float* __restrict__ V,
                 float* __restrict__ S, float* __restrict__ Z) {
    const int bh = blockIdx.x >> 3, c = blockIdx.x & 7;
    const int b = bh >> 4, h = bh & 15;
    const int tid = threadIdx.x;
    __shared__ float sK[CH][DP];   // 40 KB
    __shared__ float sV[CH][68];   // 17.4 KB
    const int r = tid >> 2, q = tid & 3;
    const float* kb = Kf + ((size_t)bh*T + c*CH)*DP;
    #pragma unroll
    for (int jj = 0; jj < 10; ++jj)
        *(float4*)&sK[r][q*40 + jj*4] = *(const float4*)(kb + (size_t)r*DP + q*40 + jj*4);
    const float* vb = V + ((size_t)(b*T + c*CH))*1024 + h*HD;
    #pragma unroll
    for (int jj = 0; jj < 4; ++jj)
        *(float4*)&sV[r][q*16 + jj*4] = *(const float4*)(vb + (size_t)r*1024 + q*16 + jj*4);
    __syncthreads();
    const int d = r;
    float4 acc[10];
    #pragma unroll
    for (int jj = 0; jj < 10; ++jj) acc[jj] = make_float4(0.f,0.f,0.f,0.f);
    for (int t = 0; t < CH; ++t) {
        const float vd = sV[t][d];
        #pragma unroll
        for (int jj = 0; jj < 10; ++jj) {
            float4 kf = *(const float4*)&sK[t][q*40 + jj*4];
            acc[jj].x += vd*kf.x; acc[jj].y += vd*kf.y;
            acc[jj].z += vd*kf.z; acc[jj].w += vd*kf.w;
        }
    }
    float* So = S + (((size_t)(bh*NC + c))*CH + d)*DP + q*40;
    #pragma unroll
    for (int jj = 0; jj < 10; ++jj) *(float4*)(So + jj*4) = acc[jj];
    if (tid < DP) {
        float z = 0.f;
        for (int t = 0; t < CH; ++t) z += sK[t][tid];
        Z[((size_t)(bh*NC + c))*DP + tid] = z;
    }
}

// In-place exclusive prefix over chunks for S and Z.
__global__ __launch_bounds__(256)
void chunk_prefix(float* __restrict__ S, float* __restrict__ Z) {
    const int bh = blockIdx.x >> 3, sl = blockIdx.x & 7;
    const int tid = threadIdx.x;
    const int per = CH*DP;  // 10240
    #pragma unroll
    for (int i = 0; i < 5; ++i) {
        const int idx = sl*1280 + i*256 + tid;
        float run = 0.f;
        for (int c = 0; c < NC; ++c) {
            float* p = S + ((size_t)(bh*NC + c))*per + idx;
            float tmp = *p; *p = run; run += tmp;
        }
    }
    if (sl == 0 && tid < DP) {
        float run = 0.f;
        for (int c = 0; c < NC; ++c) {
            float* p = Z + ((size_t)(bh*NC + c))*DP + tid;
            float tmp = *p; *p = run; run += tmp;
        }
    }
}

// Per (bh, chunk): y = Qf@P^T + tril(Qf@Kf^T)@V; den = Qf.zP + rowsum(tril(A))
__global__ __launch_bounds__(256)
void chunk_out(const float* __restrict__ Qf, const float* __restrict__ Kf,
               const float* __restrict__ V, const float* __restrict__ S,
               const float* __restrict__ Z, float* __restrict__ Y) {
    const int bh = blockIdx.x >> 3, c = blockIdx.x & 7;
    const int b = bh >> 4, h = bh & 15;
    const int tid = threadIdx.x;
    const int tx = tid & 15, ty = tid >> 4;
    __shared__ float sQ[16][65], sK[16][65], sP[16][65];
    __shared__ float sA[64][65];
    __shared__ float sV[64][68];
    __shared__ float sZ[DP];
    __shared__ float sDen[64];

    const float* qbase = Qf + ((size_t)bh*T + c*CH)*DP;
    const float* kbase = Kf + ((size_t)bh*T + c*CH)*DP;
    const float* pbase = S + ((size_t)(bh*NC + c))*CH*DP;
    const float* zbase = Z + ((size_t)(bh*NC + c))*DP;
    if (tid < DP) sZ[tid] = zbase[tid];

    float accA[4][4] = {};   // intra scores A[t][s]
    float accI[4][4] = {};   // y accumulator (starts as inter)
    const int r = tid >> 2, g4 = (tid & 3) << 2;
    for (int k0 = 0; k0 < DP; k0 += 16) {
        float4 qv = *(const float4*)(qbase + (size_t)r*DP + k0 + g4);
        float4 kv = *(const float4*)(kbase + (size_t)r*DP + k0 + g4);
        float4 pv = *(const float4*)(pbase + (size_t)r*DP + k0 + g4);
        sQ[g4+0][r]=qv.x; sQ[g4+1][r]=qv.y; sQ[g4+2][r]=qv.z; sQ[g4+3][r]=qv.w;
        sK[g4+0][r]=kv.x; sK[g4+1][r]=kv.y; sK[g4+2][r]=kv.z; sK[g4+3][r]=kv.w;
        sP[g4+0][r]=pv.x; sP[g4+1][r]=pv.y; sP[g4+2][r]=pv.z; sP[g4+3][r]=pv.w;
        __syncthreads();
        #pragma unroll
        for (int kk = 0; kk < 16; ++kk) {
            float a[4], bk[4], bp[4];
            #pragma unroll
            for (int i = 0; i < 4; ++i) a[i] = sQ[kk][ty*4+i];
            #pragma unroll
            for (int j = 0; j < 4; ++j) { bk[j] = sK[kk][tx*4+j]; bp[j] = sP[kk][tx*4+j]; }
            #pragma unroll
            for (int i = 0; i < 4; ++i)
                #pragma unroll
                for (int j = 0; j < 4; ++j) {
                    accA[i][j] += a[i]*bk[j];
                    accI[i][j] += a[i]*bp[j];
                }
        }
        __syncthreads();
    }

    // den_inter: t = tid>>2, quarter q covers 40 features
    {
        const int t = tid >> 2, q = tid & 3;
        float dp = 0.f;
        #pragma unroll
        for (int jj = 0; jj < 10; ++jj) {
            float4 qf = *(const float4*)(qbase + (size_t)t*DP + q*40 + jj*4);
            dp += qf.x*sZ[q*40+jj*4+0] + qf.y*sZ[q*40+jj*4+1]
                + qf.z*sZ[q*40+jj*4+2] + qf.w*sZ[q*40+jj*4+3];
        }
        dp += __shfl_xor(dp, 1);
        dp += __shfl_xor(dp, 2);
        if (q == 0) sDen[t] = dp;
    }

    // masked A -> LDS
    #pragma unroll
    for (int i = 0; i < 4; ++i)
        #pragma unroll
        for (int j = 0; j < 4; ++j) {
            const int t = ty*4+i, s = tx*4+j;
            sA[t][s] = (s <= t) ? accA[i][j] : 0.f;
        }
    // load V chunk
    {
        const float* vb = V + ((size_t)(b*T + c*CH))*1024 + h*HD;
        const int q = tid & 3;
        #pragma unroll
        for (int jj = 0; jj < 4; ++jj)
            *(float4*)&sV[r][q*16 + jj*4] = *(const float4*)(vb + (size_t)r*1024 + q*16 + jj*4);
    }
    __syncthreads();
    // den_intra: rowsum of masked A
    if (tid < 64) {
        float rs = 0.f;
        for (int s = 0; s < CH; ++s) rs += sA[tid][s];
        sDen[tid] += rs;
    }
    __syncthreads();

    // phase C: y += A @ V
    for (int s = 0; s < CH; ++s) {
        float a[4];
        #pragma unroll
        for (int i = 0; i < 4; ++i) a[i] = sA[ty*4+i][s];
        float4 bv = *(const float4*)&sV[s][tx*4];
        #pragma unroll
        for (int i = 0; i < 4; ++i) {
            accI[i][0] += a[i]*bv.x; accI[i][1] += a[i]*bv.y;
            accI[i][2] += a[i]*bv.z; accI[i][3] += a[i]*bv.w;
        }
    }
    // epilogue
    #pragma unroll
    for (int i = 0; i < 4; ++i) {
        const int t = ty*4+i;
        const float inv = 1.f / (sDen[t] + 1e-12f);
        float4 o = make_float4(accI[i][0]*inv, accI[i][1]*inv, accI[i][2]*inv, accI[i][3]*inv);
        *(float4*)(Y + ((size_t)(b*T + c*CH + t))*1024 + h*HD + tx*4) = o;
    }
}

extern "C" void kernel_launch(void* const* d_in, const int* in_sizes, int n_in,
                              void* d_out, int out_size, void* d_ws, size_t ws_size,
                              hipStream_t stream) {
    const float* hs = (const float*)d_in[0];
    const float* Wq = (const float*)d_in[1];
    const float* Wk = (const float*)d_in[2];
    const float* Wv = (const float*)d_in[3];
    const float* Wo = (const float*)d_in[4];
    float* out = (float*)d_out;

    float* Q  = (float*)d_ws;                        // 1024*256
    float* Kp = Q  + (size_t)B*T*NH*FD;              // 1024*256
    float* V  = Kp + (size_t)B*T*NH*FD;              // 1024*1024
    float* Y  = V  + (size_t)B*T*1024;               // 1024*1024
    float* Qf = Y  + (size_t)B*T*1024;               // 32*512*160
    float* Kf = Qf + (size_t)B*NH*T*DP;              // 32*512*160
    float* S  = Kf + (size_t)B*NH*T*DP;              // 32*8*64*160
    float* Z  = S  + (size_t)B*NH*NC*CH*DP;          // 32*8*160

    const int M = B * T;   // 1024
    dim3 blk(256);
    gemm_abt<<<dim3((NH*FD)/64, M/64), blk, 0, stream>>>(hs, Wq, Q,  M, NH*FD, 1024);
    gemm_abt<<<dim3((NH*FD)/64, M/64), blk, 0, stream>>>(hs, Wk, Kp, M, NH*FD, 1024);
    gemm_abt<<<dim3(1024/64,    M/64), blk, 0, stream>>>(hs, Wv, V,  M, 1024, 1024);
    featurize<<<dim3(B*T), blk, 0, stream>>>(Q, Kp, Qf, Kf);
    chunk_state<<<dim3(B*NH*NC), blk, 0, stream>>>(Kf, V, S, Z);
    chunk_prefix<<<dim3(B*NH*NC), blk, 0, stream>>>(S, Z);
    chunk_out<<<dim3(B*NH*NC), blk, 0, stream>>>(Qf, Kf, V, S, Z, Y);
    gemm_abt<<<dim3(1024/64,    M/64), blk, 0, stream>>>(Y, Wo, out, M, 1024, 1024);
}

// Round 3
// 254.143 us; speedup vs baseline: 4.1054x; 1.6688x over previous
//
#include <hip/hip_runtime.h>

#define T 512
#define B 2
#define NH 16
#define FD 16
#define HD 64
#define DFEAT 153
#define DP 160      // padded feature dim (zeros in [153,160))
#define CH 64       // chunk length
#define NC 8        // T/CH

typedef __attribute__((ext_vector_type(4))) short short4v;
typedef __attribute__((ext_vector_type(8))) short bf16x8;
typedef __attribute__((ext_vector_type(4))) float f32x4;

__constant__ unsigned char c_iu[120] = {
0,0,0,0,0,0,0,0,0,0,0,0,0,0,0,
1,1,1,1,1,1,1,1,1,1,1,1,1,1,
2,2,2,2,2,2,2,2,2,2,2,2,2,
3,3,3,3,3,3,3,3,3,3,3,3,
4,4,4,4,4,4,4,4,4,4,4,
5,5,5,5,5,5,5,5,5,5,
6,6,6,6,6,6,6,6,6,
7,7,7,7,7,7,7,7,
8,8,8,8,8,8,8,
9,9,9,9,9,9,
10,10,10,10,10,
11,11,11,11,
12,12,12,
13,13,
14};
__constant__ unsigned char c_ju[120] = {
1,2,3,4,5,6,7,8,9,10,11,12,13,14,15,
2,3,4,5,6,7,8,9,10,11,12,13,14,15,
3,4,5,6,7,8,9,10,11,12,13,14,15,
4,5,6,7,8,9,10,11,12,13,14,15,
5,6,7,8,9,10,11,12,13,14,15,
6,7,8,9,10,11,12,13,14,15,
7,8,9,10,11,12,13,14,15,
8,9,10,11,12,13,14,15,
9,10,11,12,13,14,15,
10,11,12,13,14,15,
11,12,13,14,15,
12,13,14,15,
13,14,15,
14,15,
15};

__device__ inline unsigned short f2bf_rne(float x) {
    unsigned u = __float_as_uint(x);
    u += 0x7fff + ((u >> 16) & 1);
    return (unsigned short)(u >> 16);
}
__device__ inline float bf2f(unsigned short h) {
    return __uint_as_float(((unsigned)h) << 16);
}

// C[M,N] = A[M,K] @ B[N,K]^T (row-major fp32), split-bf16 MFMA (hi/lo, 3 products).
// M%64==0, N%64==0, K%32==0.
__global__ __launch_bounds__(256)
void gemm_abt_mfma(const float* __restrict__ A, const float* __restrict__ Bm,
                   float* __restrict__ C, int M, int N, int K) {
    __shared__ short sA[2][64][36];   // [hi/lo][row][k], pad->18-bank stride
    __shared__ short sB[2][64][36];
    const int tid = threadIdx.x;
    const int bm = blockIdx.y * 64, bn = blockIdx.x * 64;
    const int lane = tid & 63, w = tid >> 6;
    const int wm = (w & 1) * 32, wn = (w >> 1) * 32;
    const int srow = tid >> 2, skq = (tid & 3) * 8;
    const int frow = lane & 15, fk = (lane >> 4) * 8;
    f32x4 acc[2][2] = {};
    const float* Arow = A  + (size_t)(bm + srow) * K + skq;
    const float* Brow = Bm + (size_t)(bn + srow) * K + skq;
    for (int k0 = 0; k0 < K; k0 += 32) {
        float av[8], bv[8];
        *(float4*)&av[0] = *(const float4*)(Arow + k0);
        *(float4*)&av[4] = *(const float4*)(Arow + k0 + 4);
        *(float4*)&bv[0] = *(const float4*)(Brow + k0);
        *(float4*)&bv[4] = *(const float4*)(Brow + k0 + 4);
        __syncthreads();
        #pragma unroll
        for (int j = 0; j < 8; ++j) {
            unsigned short ah = f2bf_rne(av[j]);
            unsigned short al = f2bf_rne(av[j] - bf2f(ah));
            sA[0][srow][skq + j] = (short)ah;
            sA[1][srow][skq + j] = (short)al;
            unsigned short bh = f2bf_rne(bv[j]);
            unsigned short bl = f2bf_rne(bv[j] - bf2f(bh));
            sB[0][srow][skq + j] = (short)bh;
            sB[1][srow][skq + j] = (short)bl;
        }
        __syncthreads();
        bf16x8 ah[2], al[2], bh[2], bl[2];
        #pragma unroll
        for (int i = 0; i < 2; ++i) {
            union { bf16x8 v; short4v h[2]; } u;
            u.h[0] = *(const short4v*)&sA[0][wm + i*16 + frow][fk];
            u.h[1] = *(const short4v*)&sA[0][wm + i*16 + frow][fk + 4];
            ah[i] = u.v;
            u.h[0] = *(const short4v*)&sA[1][wm + i*16 + frow][fk];
            u.h[1] = *(const short4v*)&sA[1][wm + i*16 + frow][fk + 4];
            al[i] = u.v;
            u.h[0] = *(const short4v*)&sB[0][wn + i*16 + frow][fk];
            u.h[1] = *(const short4v*)&sB[0][wn + i*16 + frow][fk + 4];
            bh[i] = u.v;
            u.h[0] = *(const short4v*)&sB[1][wn + i*16 + frow][fk];
            u.h[1] = *(const short4v*)&sB[1][wn + i*16 + frow][fk + 4];
            bl[i] = u.v;
        }
        #pragma unroll
        for (int i = 0; i < 2; ++i)
            #pragma unroll
            for (int j = 0; j < 2; ++j) {
                acc[i][j] = __builtin_amdgcn_mfma_f32_16x16x32_bf16(ah[i], bh[j], acc[i][j], 0, 0, 0);
                acc[i][j] = __builtin_amdgcn_mfma_f32_16x16x32_bf16(ah[i], bl[j], acc[i][j], 0, 0, 0);
                acc[i][j] = __builtin_amdgcn_mfma_f32_16x16x32_bf16(al[i], bh[j], acc[i][j], 0, 0, 0);
            }
    }
    const int crow0 = (lane >> 4) * 4, ccol = lane & 15;
    #pragma unroll
    for (int i = 0; i < 2; ++i)
        #pragma unroll
        for (int j = 0; j < 2; ++j)
            #pragma unroll
            for (int r = 0; r < 4; ++r)
                C[(size_t)(bm + wm + i*16 + crow0 + r) * N + bn + wn + j*16 + ccol] = acc[i][j][r];
}

// Q,K: [B*T][256] -> Qf,Kf: [bh][t][DP] feature-mapped, pad zeroed.
__global__ __launch_bounds__(256)
void featurize(const float* __restrict__ Q, const float* __restrict__ K,
               float* __restrict__ Qf, float* __restrict__ Kf) {
    const int bt = blockIdx.x;
    const int b = bt >> 9, t = bt & 511;
    const int tid = threadIdx.x;
    __shared__ float sq[256], sk[256];
    sq[tid] = Q[(size_t)bt*256 + tid];
    sk[tid] = K[(size_t)bt*256 + tid];
    __syncthreads();
    const int h = tid >> 4, sl = tid & 15;
    const float* q = sq + h*16;
    const float* k = sk + h*16;
    const size_t obase = (((size_t)(b*NH + h))*T + t)*DP + sl*10;
    float* oq = Qf + obase;
    float* ok = Kf + obase;
    #pragma unroll
    for (int m = 0; m < 10; ++m) {
        const int D = sl*10 + m;
        float fq, fk;
        if (D == 0)        { fq = 1.f; fk = 1.f; }
        else if (D < 17)   { fq = q[D-1]*0.5f; fk = k[D-1]*0.5f; }
        else if (D < 33)   { float a = q[D-17], c = k[D-17];
                             fq = a*a*0.17677669529663687f;
                             fk = c*c*0.17677669529663687f; }
        else if (D < 153)  { int p = D-33; int ii = c_iu[p], jj = c_ju[p];
                             fq = q[ii]*q[jj]*0.25f;
                             fk = k[ii]*k[jj]*0.25f; }
        else               { fq = 0.f; fk = 0.f; }
        oq[m] = fq; ok[m] = fk;
    }
}

// Per (bh, chunk): S[d][D] = sum_t V[t][d]*Kf[t][D]; z[D] = sum_t Kf[t][D]
__global__ __launch_bounds__(256)
void chunk_state(const float* __restrict__ Kf, const float* __restrict__ V,
                 float* __restrict__ S, float* __restrict__ Z) {
    const int bh = blockIdx.x >> 3, c = blockIdx.x & 7;
    const int b = bh >> 4, h = bh & 15;
    const int tid = threadIdx.x;
    __shared__ float sK[CH][DP];
    __shared__ float sV[CH][68];
    const int r = tid >> 2, q = tid & 3;
    const float* kb = Kf + ((size_t)bh*T + c*CH)*DP;
    #pragma unroll
    for (int jj = 0; jj < 10; ++jj)
        *(float4*)&sK[r][q*40 + jj*4] = *(const float4*)(kb + (size_t)r*DP + q*40 + jj*4);
    const float* vb = V + ((size_t)(b*T + c*CH))*1024 + h*HD;
    #pragma unroll
    for (int jj = 0; jj < 4; ++jj)
        *(float4*)&sV[r][q*16 + jj*4] = *(const float4*)(vb + (size_t)r*1024 + q*16 + jj*4);
    __syncthreads();
    const int d = r;
    float4 acc[10];
    #pragma unroll
    for (int jj = 0; jj < 10; ++jj) acc[jj] = make_float4(0.f,0.f,0.f,0.f);
    for (int t = 0; t < CH; ++t) {
        const float vd = sV[t][d];
        #pragma unroll
        for (int jj = 0; jj < 10; ++jj) {
            float4 kf = *(const float4*)&sK[t][q*40 + jj*4];
            acc[jj].x += vd*kf.x; acc[jj].y += vd*kf.y;
            acc[jj].z += vd*kf.z; acc[jj].w += vd*kf.w;
        }
    }
    float* So = S + (((size_t)(bh*NC + c))*CH + d)*DP + q*40;
    #pragma unroll
    for (int jj = 0; jj < 10; ++jj) *(float4*)(So + jj*4) = acc[jj];
    if (tid < DP) {
        float z = 0.f;
        for (int t = 0; t < CH; ++t) z += sK[t][tid];
        Z[((size_t)(bh*NC + c))*DP + tid] = z;
    }
}

// In-place exclusive prefix over chunks for S and Z.
__global__ __launch_bounds__(256)
void chunk_prefix(float* __restrict__ S, float* __restrict__ Z) {
    const int bh = blockIdx.x >> 3, sl = blockIdx.x & 7;
    const int tid = threadIdx.x;
    const int per = CH*DP;
    #pragma unroll
    for (int i = 0; i < 5; ++i) {
        const int idx = sl*1280 + i*256 + tid;
        float run = 0.f;
        for (int c = 0; c < NC; ++c) {
            float* p = S + ((size_t)(bh*NC + c))*per + idx;
            float tmp = *p; *p = run; run += tmp;
        }
    }
    if (sl == 0 && tid < DP) {
        float run = 0.f;
        for (int c = 0; c < NC; ++c) {
            float* p = Z + ((size_t)(bh*NC + c))*DP + tid;
            float tmp = *p; *p = run; run += tmp;
        }
    }
}

// Per (bh, chunk): y = Qf@P^T + tril(Qf@Kf^T)@V; den = Qf.zP + rowsum(tril(A))
__global__ __launch_bounds__(256)
void chunk_out(const float* __restrict__ Qf, const float* __restrict__ Kf,
               const float* __restrict__ V, const float* __restrict__ S,
               const float* __restrict__ Z, float* __restrict__ Y) {
    const int bh = blockIdx.x >> 3, c = blockIdx.x & 7;
    const int b = bh >> 4, h = bh & 15;
    const int tid = threadIdx.x;
    const int tx = tid & 15, ty = tid >> 4;
    __shared__ float sQ[16][65], sK[16][65], sP[16][65];
    __shared__ float sA[64][65];
    __shared__ float sV[64][68];
    __shared__ float sZ[DP];
    __shared__ float sDen[64];

    const float* qbase = Qf + ((size_t)bh*T + c*CH)*DP;
    const float* kbase = Kf + ((size_t)bh*T + c*CH)*DP;
    const float* pbase = S + ((size_t)(bh*NC + c))*CH*DP;
    const float* zbase = Z + ((size_t)(bh*NC + c))*DP;
    if (tid < DP) sZ[tid] = zbase[tid];

    float accA[4][4] = {};
    float accI[4][4] = {};
    const int r = tid >> 2, g4 = (tid & 3) << 2;
    for (int k0 = 0; k0 < DP; k0 += 16) {
        float4 qv = *(const float4*)(qbase + (size_t)r*DP + k0 + g4);
        float4 kv = *(const float4*)(kbase + (size_t)r*DP + k0 + g4);
        float4 pv = *(const float4*)(pbase + (size_t)r*DP + k0 + g4);
        sQ[g4+0][r]=qv.x; sQ[g4+1][r]=qv.y; sQ[g4+2][r]=qv.z; sQ[g4+3][r]=qv.w;
        sK[g4+0][r]=kv.x; sK[g4+1][r]=kv.y; sK[g4+2][r]=kv.z; sK[g4+3][r]=kv.w;
        sP[g4+0][r]=pv.x; sP[g4+1][r]=pv.y; sP[g4+2][r]=pv.z; sP[g4+3][r]=pv.w;
        __syncthreads();
        #pragma unroll
        for (int kk = 0; kk < 16; ++kk) {
            float a[4], bk[4], bp[4];
            #pragma unroll
            for (int i = 0; i < 4; ++i) a[i] = sQ[kk][ty*4+i];
            #pragma unroll
            for (int j = 0; j < 4; ++j) { bk[j] = sK[kk][tx*4+j]; bp[j] = sP[kk][tx*4+j]; }
            #pragma unroll
            for (int i = 0; i < 4; ++i)
                #pragma unroll
                for (int j = 0; j < 4; ++j) {
                    accA[i][j] += a[i]*bk[j];
                    accI[i][j] += a[i]*bp[j];
                }
        }
        __syncthreads();
    }

    {
        const int t = tid >> 2, q = tid & 3;
        float dp = 0.f;
        #pragma unroll
        for (int jj = 0; jj < 10; ++jj) {
            float4 qf = *(const float4*)(qbase + (size_t)t*DP + q*40 + jj*4);
            dp += qf.x*sZ[q*40+jj*4+0] + qf.y*sZ[q*40+jj*4+1]
                + qf.z*sZ[q*40+jj*4+2] + qf.w*sZ[q*40+jj*4+3];
        }
        dp += __shfl_xor(dp, 1);
        dp += __shfl_xor(dp, 2);
        if (q == 0) sDen[t] = dp;
    }

    #pragma unroll
    for (int i = 0; i < 4; ++i)
        #pragma unroll
        for (int j = 0; j < 4; ++j) {
            const int t = ty*4+i, s = tx*4+j;
            sA[t][s] = (s <= t) ? accA[i][j] : 0.f;
        }
    {
        const float* vb = V + ((size_t)(b*T + c*CH))*1024 + h*HD;
        const int q = tid & 3;
        #pragma unroll
        for (int jj = 0; jj < 4; ++jj)
            *(float4*)&sV[r][q*16 + jj*4] = *(const float4*)(vb + (size_t)r*1024 + q*16 + jj*4);
    }
    __syncthreads();
    if (tid < 64) {
        float rs = 0.f;
        for (int s = 0; s < CH; ++s) rs += sA[tid][s];
        sDen[tid] += rs;
    }
    __syncthreads();

    for (int s = 0; s < CH; ++s) {
        float a[4];
        #pragma unroll
        for (int i = 0; i < 4; ++i) a[i] = sA[ty*4+i][s];
        float4 bv = *(const float4*)&sV[s][tx*4];
        #pragma unroll
        for (int i = 0; i < 4; ++i) {
            accI[i][0] += a[i]*bv.x; accI[i][1] += a[i]*bv.y;
            accI[i][2] += a[i]*bv.z; accI[i][3] += a[i]*bv.w;
        }
    }
    #pragma unroll
    for (int i = 0; i < 4; ++i) {
        const int t = ty*4+i;
        const float inv = 1.f / (sDen[t] + 1e-12f);
        float4 o = make_float4(accI[i][0]*inv, accI[i][1]*inv, accI[i][2]*inv, accI[i][3]*inv);
        *(float4*)(Y + ((size_t)(b*T + c*CH + t))*1024 + h*HD + tx*4) = o;
    }
}

extern "C" void kernel_launch(void* const* d_in, const int* in_sizes, int n_in,
                              void* d_out, int out_size, void* d_ws, size_t ws_size,
                              hipStream_t stream) {
    const float* hs = (const float*)d_in[0];
    const float* Wq = (const float*)d_in[1];
    const float* Wk = (const float*)d_in[2];
    const float* Wv = (const float*)d_in[3];
    const float* Wo = (const float*)d_in[4];
    float* out = (float*)d_out;

    float* Q  = (float*)d_ws;
    float* Kp = Q  + (size_t)B*T*NH*FD;
    float* V  = Kp + (size_t)B*T*NH*FD;
    float* Y  = V  + (size_t)B*T*1024;
    float* Qf = Y  + (size_t)B*T*1024;
    float* Kf = Qf + (size_t)B*NH*T*DP;
    float* S  = Kf + (size_t)B*NH*T*DP;
    float* Z  = S  + (size_t)B*NH*NC*CH*DP;

    const int M = B * T;
    dim3 blk(256);
    gemm_abt_mfma<<<dim3((NH*FD)/64, M/64), blk, 0, stream>>>(hs, Wq, Q,  M, NH*FD, 1024);
    gemm_abt_mfma<<<dim3((NH*FD)/64, M/64), blk, 0, stream>>>(hs, Wk, Kp, M, NH*FD, 1024);
    gemm_abt_mfma<<<dim3(1024/64,    M/64), blk, 0, stream>>>(hs, Wv, V,  M, 1024, 1024);
    featurize<<<dim3(B*T), blk, 0, stream>>>(Q, Kp, Qf, Kf);
    chunk_state<<<dim3(B*NH*NC), blk, 0, stream>>>(Kf, V, S, Z);
    chunk_prefix<<<dim3(B*NH*NC), blk, 0, stream>>>(S, Z);
    chunk_out<<<dim3(B*NH*NC), blk, 0, stream>>>(Qf, Kf, V, S, Z, Y);
    gemm_abt_mfma<<<dim3(1024/64,    M/64), blk, 0, stream>>>(Y, Wo, out, M, 1024, 1024);
}

// Round 4
// 177.670 us; speedup vs baseline: 5.8725x; 1.4304x over previous
//
#include <hip/hip_runtime.h>

#define T 512
#define B 2
#define NH 16
#define FD 16
#define HD 64
#define DP 160      // padded feature dim (zeros in [153,160))
#define CH 64
#define NC 8

typedef __attribute__((ext_vector_type(4))) short short4v;
typedef __attribute__((ext_vector_type(8))) short bf16x8;
typedef __attribute__((ext_vector_type(4))) float f32x4;

__constant__ unsigned char c_iu[120] = {
0,0,0,0,0,0,0,0,0,0,0,0,0,0,0,
1,1,1,1,1,1,1,1,1,1,1,1,1,1,
2,2,2,2,2,2,2,2,2,2,2,2,2,
3,3,3,3,3,3,3,3,3,3,3,3,
4,4,4,4,4,4,4,4,4,4,4,
5,5,5,5,5,5,5,5,5,5,
6,6,6,6,6,6,6,6,6,
7,7,7,7,7,7,7,7,
8,8,8,8,8,8,8,
9,9,9,9,9,9,
10,10,10,10,10,
11,11,11,11,
12,12,12,
13,13,
14};
__constant__ unsigned char c_ju[120] = {
1,2,3,4,5,6,7,8,9,10,11,12,13,14,15,
2,3,4,5,6,7,8,9,10,11,12,13,14,15,
3,4,5,6,7,8,9,10,11,12,13,14,15,
4,5,6,7,8,9,10,11,12,13,14,15,
5,6,7,8,9,10,11,12,13,14,15,
6,7,8,9,10,11,12,13,14,15,
7,8,9,10,11,12,13,14,15,
8,9,10,11,12,13,14,15,
9,10,11,12,13,14,15,
10,11,12,13,14,15,
11,12,13,14,15,
12,13,14,15,
13,14,15,
14,15,
15};

__device__ inline unsigned short f2bf_rne(float x) {
    unsigned u = __float_as_uint(x);
    u += 0x7fff + ((u >> 16) & 1);
    return (unsigned short)(u >> 16);
}
__device__ inline float bf2f(unsigned short h) {
    return __uint_as_float(((unsigned)h) << 16);
}
__device__ inline void split8f(const float* x, bf16x8& hi, bf16x8& lo) {
    #pragma unroll
    for (int e = 0; e < 8; ++e) {
        unsigned short h = f2bf_rne(x[e]);
        hi[e] = (short)h;
        lo[e] = (short)f2bf_rne(x[e] - bf2f(h));
    }
}
__device__ inline f32x4 mfma3(bf16x8 ah, bf16x8 al, bf16x8 bh, bf16x8 bl, f32x4 acc) {
    acc = __builtin_amdgcn_mfma_f32_16x16x32_bf16(ah, bh, acc, 0, 0, 0);
    acc = __builtin_amdgcn_mfma_f32_16x16x32_bf16(ah, bl, acc, 0, 0, 0);
    acc = __builtin_amdgcn_mfma_f32_16x16x32_bf16(al, bh, acc, 0, 0, 0);
    return acc;
}

// ---- 1) pre-convert hs + weights to bf16 hi/lo planes; concat Wq|Wk|Wv ----
__global__ __launch_bounds__(256)
void preconv(const float* __restrict__ hs, const float* __restrict__ Wq,
             const float* __restrict__ Wk, const float* __restrict__ Wv,
             const float* __restrict__ Wo,
             short* __restrict__ hsh, short* __restrict__ hsl,
             short* __restrict__ Wch, short* __restrict__ Wcl,
             short* __restrict__ Woh, short* __restrict__ Wol) {
    const int i4 = blockIdx.x * 256 + threadIdx.x;   // float4 index, 917504 total
    const float* src; short *dh, *dl; size_t off4;
    if (i4 < 262144)      { src = hs; dh = hsh;          dl = hsl;          off4 = i4; }
    else if (i4 < 327680) { src = Wq; dh = Wch;          dl = Wcl;          off4 = i4 - 262144; }
    else if (i4 < 393216) { src = Wk; dh = Wch + 262144; dl = Wcl + 262144; off4 = i4 - 327680; }
    else if (i4 < 655360) { src = Wv; dh = Wch + 524288; dl = Wcl + 524288; off4 = i4 - 393216; }
    else                  { src = Wo; dh = Woh;          dl = Wol;          off4 = i4 - 655360; }
    float4 v = *(const float4*)(src + off4 * 4);
    float vv[4] = {v.x, v.y, v.z, v.w};
    short4v sh, sl;
    #pragma unroll
    for (int e = 0; e < 4; ++e) {
        unsigned short h = f2bf_rne(vv[e]);
        sh[e] = (short)h;
        sl[e] = (short)f2bf_rne(vv[e] - bf2f(h));
    }
    *(short4v*)(dh + off4 * 4) = sh;
    *(short4v*)(dl + off4 * 4) = sl;
}

// ---- 2) C[M,N] = A[M,K] @ B[N,K]^T, inputs pre-split bf16 hi/lo, fp32 out ----
__global__ __launch_bounds__(256)
void gemm_pair(const short* __restrict__ Ah, const short* __restrict__ Al,
               const short* __restrict__ Bh, const short* __restrict__ Bl,
               float* __restrict__ C, int M, int N, int K) {
    __shared__ short sAh[64][40], sAl[64][40], sBh[64][40], sBl[64][40];
    const int tid = threadIdx.x;
    const int bm = blockIdx.y * 64, bn = blockIdx.x * 64;
    const int lane = tid & 63, w = tid >> 6;
    const int wm = (w & 1) * 32, wn = (w >> 1) * 32;
    const int srow = tid >> 2, skq = (tid & 3) * 8;
    const int fm = lane & 15, fk = (lane >> 4) * 8;
    f32x4 acc[2][2] = {};
    const short* pAh = Ah + (size_t)(bm + srow) * K + skq;
    const short* pAl = Al + (size_t)(bm + srow) * K + skq;
    const short* pBh = Bh + (size_t)(bn + srow) * K + skq;
    const short* pBl = Bl + (size_t)(bn + srow) * K + skq;
    for (int k0 = 0; k0 < K; k0 += 32) {
        bf16x8 vah = *(const bf16x8*)(pAh + k0);
        bf16x8 val = *(const bf16x8*)(pAl + k0);
        bf16x8 vbh = *(const bf16x8*)(pBh + k0);
        bf16x8 vbl = *(const bf16x8*)(pBl + k0);
        __syncthreads();
        *(bf16x8*)&sAh[srow][skq] = vah;
        *(bf16x8*)&sAl[srow][skq] = val;
        *(bf16x8*)&sBh[srow][skq] = vbh;
        *(bf16x8*)&sBl[srow][skq] = vbl;
        __syncthreads();
        bf16x8 ah[2], al[2], bh[2], bl[2];
        #pragma unroll
        for (int i = 0; i < 2; ++i) {
            ah[i] = *(const bf16x8*)&sAh[wm + i*16 + fm][fk];
            al[i] = *(const bf16x8*)&sAl[wm + i*16 + fm][fk];
            bh[i] = *(const bf16x8*)&sBh[wn + i*16 + fm][fk];
            bl[i] = *(const bf16x8*)&sBl[wn + i*16 + fm][fk];
        }
        #pragma unroll
        for (int i = 0; i < 2; ++i)
            #pragma unroll
            for (int j = 0; j < 2; ++j)
                acc[i][j] = mfma3(ah[i], al[i], bh[j], bl[j], acc[i][j]);
    }
    const int crow0 = (lane >> 4) * 4, ccol = lane & 15;
    #pragma unroll
    for (int i = 0; i < 2; ++i)
        #pragma unroll
        for (int j = 0; j < 2; ++j)
            #pragma unroll
            for (int r = 0; r < 4; ++r)
                C[(size_t)(bm + wm + i*16 + crow0 + r) * N + bn + wn + j*16 + ccol] = acc[i][j][r];
}

// ---- 3) featurize: Cp cols [0,256)=Q, [256,512)=K -> Qf/Kf bf16 hi/lo planes ----
__global__ __launch_bounds__(256)
void featurize(const float* __restrict__ Cp,
               short* __restrict__ Qfh, short* __restrict__ Qfl,
               short* __restrict__ Kfh, short* __restrict__ Kfl) {
    const int bt = blockIdx.x;
    const int b = bt >> 9, t = bt & 511;
    const int tid = threadIdx.x;
    __shared__ float sq[256], sk[256];
    sq[tid] = Cp[(size_t)bt * 1536 + tid];
    sk[tid] = Cp[(size_t)bt * 1536 + 256 + tid];
    __syncthreads();
    const int h = tid >> 4, sl = tid & 15;
    const float* q = sq + h * 16;
    const float* k = sk + h * 16;
    const size_t obase = (((size_t)(b * NH + h)) * T + t) * DP + sl * 10;
    #pragma unroll
    for (int m = 0; m < 10; ++m) {
        const int D = sl * 10 + m;
        float fq, fk;
        if (D == 0)        { fq = 1.f; fk = 1.f; }
        else if (D < 17)   { fq = q[D-1] * 0.5f; fk = k[D-1] * 0.5f; }
        else if (D < 33)   { float a = q[D-17], c = k[D-17];
                             fq = a * a * 0.17677669529663687f;
                             fk = c * c * 0.17677669529663687f; }
        else if (D < 153)  { int p = D - 33; int ii = c_iu[p], jj = c_ju[p];
                             fq = q[ii] * q[jj] * 0.25f;
                             fk = k[ii] * k[jj] * 0.25f; }
        else               { fq = 0.f; fk = 0.f; }
        unsigned short qh = f2bf_rne(fq);
        unsigned short kh = f2bf_rne(fk);
        Qfh[obase + m] = (short)qh;
        Qfl[obase + m] = (short)f2bf_rne(fq - bf2f(qh));
        Kfh[obase + m] = (short)kh;
        Kfl[obase + m] = (short)f2bf_rne(fk - bf2f(kh));
    }
}

// ---- 4) chunk_state: per (bh,c): S[d][D] = sum_t V[t][d]*Kf[t][D]; z; VT planes ----
__global__ __launch_bounds__(256)
void chunk_state(const short* __restrict__ Kfh, const short* __restrict__ Kfl,
                 const float* __restrict__ Cp,
                 float* __restrict__ S, float* __restrict__ Z,
                 short* __restrict__ VTh, short* __restrict__ VTl) {
    const int bh = blockIdx.x >> 3, c = blockIdx.x & 7;
    const int b = bh >> 4, h = bh & 15;
    const int tid = threadIdx.x;
    const int lane = tid & 63, w = tid >> 6;
    const int wm = (w & 1) * 32, wn = (w >> 1) * 80;
    __shared__ short sVTh[64][72], sVTl[64][72];     // [d][t]
    __shared__ short sKTh[160][72], sKTl[160][72];   // [D][t]
    const int r = tid >> 2, q = tid & 3;
    // stage V tile transposed + split (V lives in Cp cols [512,1536))
    {
        const float* vsrc = Cp + (size_t)(b*T + c*CH + r) * 1536 + 512 + h*HD + q*16;
        float vf[16];
        *(float4*)&vf[0]  = *(const float4*)(vsrc + 0);
        *(float4*)&vf[4]  = *(const float4*)(vsrc + 4);
        *(float4*)&vf[8]  = *(const float4*)(vsrc + 8);
        *(float4*)&vf[12] = *(const float4*)(vsrc + 12);
        #pragma unroll
        for (int e = 0; e < 16; ++e) {
            const int d = q*16 + e;
            unsigned short hh = f2bf_rne(vf[e]);
            sVTh[d][r] = (short)hh;
            sVTl[d][r] = (short)f2bf_rne(vf[e] - bf2f(hh));
        }
    }
    // stage Kf transposed (already bf16 pairs)
    {
        const short* kh = Kfh + ((size_t)bh*T + c*CH + r) * DP + q*40;
        const short* kl = Kfl + ((size_t)bh*T + c*CH + r) * DP + q*40;
        #pragma unroll
        for (int bx = 0; bx < 5; ++bx) {
            bf16x8 vh = *(const bf16x8*)(kh + bx*8);
            bf16x8 vl = *(const bf16x8*)(kl + bx*8);
            #pragma unroll
            for (int e = 0; e < 8; ++e) {
                sKTh[q*40 + bx*8 + e][r] = vh[e];
                sKTl[q*40 + bx*8 + e][r] = vl[e];
            }
        }
    }
    __syncthreads();
    // z[D] = sum_t Kf[t][D]
    if (tid < DP) {
        float zz = 0.f;
        for (int tt = 0; tt < CH; ++tt)
            zz += bf2f((unsigned short)sKTh[tid][tt]) + bf2f((unsigned short)sKTl[tid][tt]);
        Z[((size_t)(bh*NC + c)) * DP + tid] = zz;
    }
    // S = VT @ KT^T via MFMA: C[m=d][n=D], k=t
    const int fm = lane & 15, fk = (lane >> 4) * 8;
    f32x4 acc[2][5] = {};
    #pragma unroll
    for (int k0 = 0; k0 < 64; k0 += 32) {
        bf16x8 ah[2], al[2];
        #pragma unroll
        for (int i = 0; i < 2; ++i) {
            ah[i] = *(const bf16x8*)&sVTh[wm + i*16 + fm][k0 + fk];
            al[i] = *(const bf16x8*)&sVTl[wm + i*16 + fm][k0 + fk];
        }
        #pragma unroll
        for (int j = 0; j < 5; ++j) {
            bf16x8 bh = *(const bf16x8*)&sKTh[wn + j*16 + fm][k0 + fk];
            bf16x8 bl = *(const bf16x8*)&sKTl[wn + j*16 + fm][k0 + fk];
            #pragma unroll
            for (int i = 0; i < 2; ++i)
                acc[i][j] = mfma3(ah[i], al[i], bh, bl, acc[i][j]);
        }
    }
    const int crow0 = (lane >> 4) * 4, ccol = lane & 15;
    float* Sb = S + ((size_t)(bh*NC + c)) * CH * DP;
    #pragma unroll
    for (int i = 0; i < 2; ++i)
        #pragma unroll
        for (int j = 0; j < 5; ++j)
            #pragma unroll
            for (int rr = 0; rr < 4; ++rr)
                Sb[(size_t)(wm + i*16 + crow0 + rr) * DP + wn + j*16 + ccol] = acc[i][j][rr];
    // dump VT planes for chunk_out
    {
        short* oh = VTh + ((size_t)(bh*NC + c)) * 4096;
        short* ol = VTl + ((size_t)(bh*NC + c)) * 4096;
        const int d = tid >> 2, t0 = (tid & 3) * 16;
        *(bf16x8*)(oh + d*64 + t0)     = *(const bf16x8*)&sVTh[d][t0];
        *(bf16x8*)(oh + d*64 + t0 + 8) = *(const bf16x8*)&sVTh[d][t0 + 8];
        *(bf16x8*)(ol + d*64 + t0)     = *(const bf16x8*)&sVTl[d][t0];
        *(bf16x8*)(ol + d*64 + t0 + 8) = *(const bf16x8*)&sVTl[d][t0 + 8];
    }
}

// ---- 5) chunk_out: y = Qf@P^T + tril(Qf@Kf^T)@V, den; writes Y bf16 hi/lo ----
__global__ __launch_bounds__(256)
void chunk_out(const short* __restrict__ Qfh, const short* __restrict__ Qfl,
               const short* __restrict__ Kfh, const short* __restrict__ Kfl,
               const float* __restrict__ S, const float* __restrict__ Z,
               const short* __restrict__ VTh, const short* __restrict__ VTl,
               short* __restrict__ Yh, short* __restrict__ Yl) {
    const int bh = blockIdx.x >> 3, c = blockIdx.x & 7;
    const int b = bh >> 4, h = bh & 15;
    const int tid = threadIdx.x;
    const int lane = tid & 63, w = tid >> 6;
    const int wm = (w & 1) * 32, wn = (w >> 1) * 32;
    const int fm = lane & 15, fk = (lane >> 4) * 8;
    __shared__ float sP[64][164];   // prefix state sum, fp32
    __shared__ float sA[64][68];    // masked intra scores
    __shared__ float sZ[DP];
    __shared__ float sDen[64];
    // 1) sum S, Z over chunks < c
    for (int e = tid; e < 2560; e += 256) {
        const int d = e / 40, D4 = (e % 40) * 4;
        float4 a = make_float4(0.f, 0.f, 0.f, 0.f);
        for (int cc = 0; cc < c; ++cc) {
            float4 s = *(const float4*)(S + (((size_t)(bh*NC + cc)) * CH + d) * DP + D4);
            a.x += s.x; a.y += s.y; a.z += s.z; a.w += s.w;
        }
        *(float4*)&sP[d][D4] = a;
    }
    if (tid < DP) {
        float zz = 0.f;
        for (int cc = 0; cc < c; ++cc) zz += Z[((size_t)(bh*NC + cc)) * DP + tid];
        sZ[tid] = zz;
    }
    __syncthreads();
    // 2) main K-loop over feature dim
    f32x4 accA[2][2] = {};   // intra scores
    f32x4 accI[2][2] = {};   // output accumulator (inter first)
    const size_t qkbase = ((size_t)bh*T + c*CH);
    for (int k0 = 0; k0 < DP; k0 += 32) {
        bf16x8 qh[2], ql[2];
        #pragma unroll
        for (int i = 0; i < 2; ++i) {
            const size_t off = (qkbase + wm + i*16 + fm) * DP + k0 + fk;
            qh[i] = *(const bf16x8*)(Qfh + off);
            ql[i] = *(const bf16x8*)(Qfl + off);
        }
        #pragma unroll
        for (int j = 0; j < 2; ++j) {
            const size_t koff = (qkbase + wn + j*16 + fm) * DP + k0 + fk;
            bf16x8 kh = *(const bf16x8*)(Kfh + koff);
            bf16x8 kl = *(const bf16x8*)(Kfl + koff);
            float pf[8];
            *(float4*)&pf[0] = *(const float4*)&sP[wn + j*16 + fm][k0 + fk];
            *(float4*)&pf[4] = *(const float4*)&sP[wn + j*16 + fm][k0 + fk + 4];
            bf16x8 ph, pl;
            split8f(pf, ph, pl);
            #pragma unroll
            for (int i = 0; i < 2; ++i) {
                accA[i][j] = mfma3(qh[i], ql[i], kh, kl, accA[i][j]);
                accI[i][j] = mfma3(qh[i], ql[i], ph, pl, accI[i][j]);
            }
        }
    }
    // 3) den_inter (per row t)
    {
        const int t_ = tid >> 2, q4 = tid & 3;
        const short* qph = Qfh + (qkbase + t_) * DP + q4*40;
        const short* qpl = Qfl + (qkbase + t_) * DP + q4*40;
        float dp = 0.f;
        #pragma unroll
        for (int bx = 0; bx < 5; ++bx) {
            bf16x8 vh = *(const bf16x8*)(qph + bx*8);
            bf16x8 vl = *(const bf16x8*)(qpl + bx*8);
            #pragma unroll
            for (int e = 0; e < 8; ++e)
                dp += (bf2f((unsigned short)vh[e]) + bf2f((unsigned short)vl[e])) * sZ[q4*40 + bx*8 + e];
        }
        dp += __shfl_xor(dp, 1);
        dp += __shfl_xor(dp, 2);
        if (q4 == 0) sDen[t_] = dp;
    }
    // 4) masked A -> LDS
    {
        const int crow0 = (lane >> 4) * 4, ccol = lane & 15;
        #pragma unroll
        for (int i = 0; i < 2; ++i)
            #pragma unroll
            for (int j = 0; j < 2; ++j)
                #pragma unroll
                for (int rr = 0; rr < 4; ++rr) {
                    const int t_ = wm + i*16 + crow0 + rr, s_ = wn + j*16 + ccol;
                    sA[t_][s_] = (s_ <= t_) ? accA[i][j][rr] : 0.f;
                }
    }
    __syncthreads();
    // 5) den_intra rowsum
    if (tid < 64) {
        float rs = 0.f;
        for (int s_ = 0; s_ < CH; ++s_) rs += sA[tid][s_];
        sDen[tid] += rs;
    }
    __syncthreads();
    // 6) y += A @ V  (B from global VT planes)
    const size_t vtbase = ((size_t)(bh*NC + c)) * 4096;
    #pragma unroll
    for (int k0 = 0; k0 < 64; k0 += 32) {
        bf16x8 ah[2], al[2];
        #pragma unroll
        for (int i = 0; i < 2; ++i) {
            float af[8];
            *(float4*)&af[0] = *(const float4*)&sA[wm + i*16 + fm][k0 + fk];
            *(float4*)&af[4] = *(const float4*)&sA[wm + i*16 + fm][k0 + fk + 4];
            split8f(af, ah[i], al[i]);
        }
        #pragma unroll
        for (int j = 0; j < 2; ++j) {
            bf16x8 bhf = *(const bf16x8*)(VTh + vtbase + (size_t)(wn + j*16 + fm) * 64 + k0 + fk);
            bf16x8 blf = *(const bf16x8*)(VTl + vtbase + (size_t)(wn + j*16 + fm) * 64 + k0 + fk);
            #pragma unroll
            for (int i = 0; i < 2; ++i)
                accI[i][j] = mfma3(ah[i], al[i], bhf, blf, accI[i][j]);
        }
    }
    // 7) epilogue: divide by den, split to bf16 pair, store Y
    {
        const int crow0 = (lane >> 4) * 4, ccol = lane & 15;
        #pragma unroll
        for (int i = 0; i < 2; ++i)
            #pragma unroll
            for (int rr = 0; rr < 4; ++rr) {
                const int t_ = wm + i*16 + crow0 + rr;
                const float inv = 1.f / (sDen[t_] + 1e-12f);
                const size_t grow = (size_t)(b*T + c*CH + t_) * 1024 + h*HD;
                #pragma unroll
                for (int j = 0; j < 2; ++j) {
                    const float y = accI[i][j][rr] * inv;
                    unsigned short hh = f2bf_rne(y);
                    Yh[grow + wn + j*16 + ccol] = (short)hh;
                    Yl[grow + wn + j*16 + ccol] = (short)f2bf_rne(y - bf2f(hh));
                }
            }
    }
}

extern "C" void kernel_launch(void* const* d_in, const int* in_sizes, int n_in,
                              void* d_out, int out_size, void* d_ws, size_t ws_size,
                              hipStream_t stream) {
    const float* hs = (const float*)d_in[0];
    const float* Wq = (const float*)d_in[1];
    const float* Wk = (const float*)d_in[2];
    const float* Wv = (const float*)d_in[3];
    const float* Wo = (const float*)d_in[4];
    float* out = (float*)d_out;

    char* p = (char*)d_ws;
    float* Cp  = (float*)p; p += (size_t)1024*1536*4;   // proj output [bt][Q|K|V]
    short* hsh = (short*)p; p += (size_t)1048576*2;
    short* hsl = (short*)p; p += (size_t)1048576*2;
    short* Wch = (short*)p; p += (size_t)1536*1024*2;
    short* Wcl = (short*)p; p += (size_t)1536*1024*2;
    short* Woh = (short*)p; p += (size_t)1048576*2;
    short* Wol = (short*)p; p += (size_t)1048576*2;
    short* Qfh = (short*)p; p += (size_t)32*512*DP*2;
    short* Qfl = (short*)p; p += (size_t)32*512*DP*2;
    short* Kfh = (short*)p; p += (size_t)32*512*DP*2;
    short* Kfl = (short*)p; p += (size_t)32*512*DP*2;
    float* S   = (float*)p; p += (size_t)32*NC*CH*DP*4;
    float* Z   = (float*)p; p += (size_t)32*NC*DP*4;
    short* VTh = (short*)p; p += (size_t)32*NC*4096*2;
    short* VTl = (short*)p; p += (size_t)32*NC*4096*2;
    short* Yh  = (short*)p; p += (size_t)1048576*2;
    short* Yl  = (short*)p; p += (size_t)1048576*2;

    dim3 blk(256);
    preconv<<<dim3(3584), blk, 0, stream>>>(hs, Wq, Wk, Wv, Wo, hsh, hsl, Wch, Wcl, Woh, Wol);
    gemm_pair<<<dim3(24, 16), blk, 0, stream>>>(hsh, hsl, Wch, Wcl, Cp, 1024, 1536, 1024);
    featurize<<<dim3(1024), blk, 0, stream>>>(Cp, Qfh, Qfl, Kfh, Kfl);
    chunk_state<<<dim3(256), blk, 0, stream>>>(Kfh, Kfl, Cp, S, Z, VTh, VTl);
    chunk_out<<<dim3(256), blk, 0, stream>>>(Qfh, Qfl, Kfh, Kfl, S, Z, VTh, VTl, Yh, Yl);
    gemm_pair<<<dim3(16, 16), blk, 0, stream>>>(Yh, Yl, Woh, Wol, out, 1024, 1024, 1024);
}

// Round 5
// 153.080 us; speedup vs baseline: 6.8158x; 1.1606x over previous
//
#include <hip/hip_runtime.h>

#define T 512
#define B 2
#define NH 16
#define FD 16
#define HD 64
#define DP 160      // padded feature dim (zeros in [153,160))
#define CH 64
#define NC 8

typedef __attribute__((ext_vector_type(4))) short short4v;
typedef __attribute__((ext_vector_type(8))) short bf16x8;
typedef __attribute__((ext_vector_type(4))) float f32x4;

__constant__ unsigned char c_iu[120] = {
0,0,0,0,0,0,0,0,0,0,0,0,0,0,0,
1,1,1,1,1,1,1,1,1,1,1,1,1,1,
2,2,2,2,2,2,2,2,2,2,2,2,2,
3,3,3,3,3,3,3,3,3,3,3,3,
4,4,4,4,4,4,4,4,4,4,4,
5,5,5,5,5,5,5,5,5,5,
6,6,6,6,6,6,6,6,6,
7,7,7,7,7,7,7,7,
8,8,8,8,8,8,8,
9,9,9,9,9,9,
10,10,10,10,10,
11,11,11,11,
12,12,12,
13,13,
14};
__constant__ unsigned char c_ju[120] = {
1,2,3,4,5,6,7,8,9,10,11,12,13,14,15,
2,3,4,5,6,7,8,9,10,11,12,13,14,15,
3,4,5,6,7,8,9,10,11,12,13,14,15,
4,5,6,7,8,9,10,11,12,13,14,15,
5,6,7,8,9,10,11,12,13,14,15,
6,7,8,9,10,11,12,13,14,15,
7,8,9,10,11,12,13,14,15,
8,9,10,11,12,13,14,15,
9,10,11,12,13,14,15,
10,11,12,13,14,15,
11,12,13,14,15,
12,13,14,15,
13,14,15,
14,15,
15};

__device__ inline unsigned short f2bf_rne(float x) {
    unsigned u = __float_as_uint(x);
    u += 0x7fff + ((u >> 16) & 1);
    return (unsigned short)(u >> 16);
}
__device__ inline float bf2f(unsigned short h) {
    return __uint_as_float(((unsigned)h) << 16);
}
__device__ inline bf16x8 pack8(const float* x) {
    bf16x8 r;
    #pragma unroll
    for (int e = 0; e < 8; ++e) r[e] = (short)f2bf_rne(x[e]);
    return r;
}
__device__ inline f32x4 mfma1(bf16x8 a, bf16x8 b, f32x4 acc) {
    return __builtin_amdgcn_mfma_f32_16x16x32_bf16(a, b, acc, 0, 0, 0);
}
__device__ inline f32x4 mfma3(bf16x8 ah, bf16x8 al, bf16x8 bh, bf16x8 bl, f32x4 acc) {
    acc = __builtin_amdgcn_mfma_f32_16x16x32_bf16(ah, bh, acc, 0, 0, 0);
    acc = __builtin_amdgcn_mfma_f32_16x16x32_bf16(ah, bl, acc, 0, 0, 0);
    acc = __builtin_amdgcn_mfma_f32_16x16x32_bf16(al, bh, acc, 0, 0, 0);
    return acc;
}

// ---- 1) pre-convert hs + weights to bf16 hi/lo planes; concat Wq|Wk|Wv ----
__global__ __launch_bounds__(256)
void preconv(const float* __restrict__ hs, const float* __restrict__ Wq,
             const float* __restrict__ Wk, const float* __restrict__ Wv,
             const float* __restrict__ Wo,
             short* __restrict__ hsh, short* __restrict__ hsl,
             short* __restrict__ Wch, short* __restrict__ Wcl,
             short* __restrict__ Woh, short* __restrict__ Wol) {
    const int i4 = blockIdx.x * 256 + threadIdx.x;   // float4 index, 917504 total
    const float* src; short *dh, *dl; size_t off4;
    if (i4 < 262144)      { src = hs; dh = hsh;          dl = hsl;          off4 = i4; }
    else if (i4 < 327680) { src = Wq; dh = Wch;          dl = Wcl;          off4 = i4 - 262144; }
    else if (i4 < 393216) { src = Wk; dh = Wch + 262144; dl = Wcl + 262144; off4 = i4 - 327680; }
    else if (i4 < 655360) { src = Wv; dh = Wch + 524288; dl = Wcl + 524288; off4 = i4 - 393216; }
    else                  { src = Wo; dh = Woh;          dl = Wol;          off4 = i4 - 655360; }
    float4 v = *(const float4*)(src + off4 * 4);
    float vv[4] = {v.x, v.y, v.z, v.w};
    short4v sh, sl;
    #pragma unroll
    for (int e = 0; e < 4; ++e) {
        unsigned short h = f2bf_rne(vv[e]);
        sh[e] = (short)h;
        sl[e] = (short)f2bf_rne(vv[e] - bf2f(h));
    }
    *(short4v*)(dh + off4 * 4) = sh;
    *(short4v*)(dl + off4 * 4) = sl;
}

// ---- 2) proj GEMM: Cp[1024][1536] = hs @ Wc^T, 64x96 tile, split-bf16 ----
__global__ __launch_bounds__(256)
void gemm_proj(const short* __restrict__ Ah, const short* __restrict__ Al,
               const short* __restrict__ Bh, const short* __restrict__ Bl,
               float* __restrict__ C) {
    __shared__ short sAh[64][40], sAl[64][40];
    __shared__ short sBh[96][40], sBl[96][40];
    const int tid = threadIdx.x;
    const int bm = blockIdx.y * 64, bn = blockIdx.x * 96;
    const int lane = tid & 63, w = tid >> 6;
    const int wm = (w & 1) * 32, wn = (w >> 1) * 48;
    const int srA = tid >> 2, skA = (tid & 3) * 8;
    const int srB = tid >> 1, skB = (tid & 1) * 16;
    const int fm = lane & 15, fk = (lane >> 4) * 8;
    f32x4 acc[2][3] = {};
    const short* pAh = Ah + (size_t)(bm + srA) * 1024 + skA;
    const short* pAl = Al + (size_t)(bm + srA) * 1024 + skA;
    const short* pBh = Bh + (size_t)(bn + (srB < 96 ? srB : 0)) * 1024 + skB;
    const short* pBl = Bl + (size_t)(bn + (srB < 96 ? srB : 0)) * 1024 + skB;
    for (int k0 = 0; k0 < 1024; k0 += 32) {
        bf16x8 vah = *(const bf16x8*)(pAh + k0);
        bf16x8 val = *(const bf16x8*)(pAl + k0);
        bf16x8 vbh0, vbh1, vbl0, vbl1;
        if (tid < 192) {
            vbh0 = *(const bf16x8*)(pBh + k0);
            vbh1 = *(const bf16x8*)(pBh + k0 + 8);
            vbl0 = *(const bf16x8*)(pBl + k0);
            vbl1 = *(const bf16x8*)(pBl + k0 + 8);
        }
        __syncthreads();
        *(bf16x8*)&sAh[srA][skA] = vah;
        *(bf16x8*)&sAl[srA][skA] = val;
        if (tid < 192) {
            *(bf16x8*)&sBh[srB][skB]     = vbh0;
            *(bf16x8*)&sBh[srB][skB + 8] = vbh1;
            *(bf16x8*)&sBl[srB][skB]     = vbl0;
            *(bf16x8*)&sBl[srB][skB + 8] = vbl1;
        }
        __syncthreads();
        bf16x8 ah[2], al[2];
        #pragma unroll
        for (int i = 0; i < 2; ++i) {
            ah[i] = *(const bf16x8*)&sAh[wm + i*16 + fm][fk];
            al[i] = *(const bf16x8*)&sAl[wm + i*16 + fm][fk];
        }
        #pragma unroll
        for (int j = 0; j < 3; ++j) {
            bf16x8 bh = *(const bf16x8*)&sBh[wn + j*16 + fm][fk];
            bf16x8 bl = *(const bf16x8*)&sBl[wn + j*16 + fm][fk];
            #pragma unroll
            for (int i = 0; i < 2; ++i)
                acc[i][j] = mfma3(ah[i], al[i], bh, bl, acc[i][j]);
        }
    }
    const int crow0 = (lane >> 4) * 4, ccol = lane & 15;
    #pragma unroll
    for (int i = 0; i < 2; ++i)
        #pragma unroll
        for (int j = 0; j < 3; ++j)
            #pragma unroll
            for (int r = 0; r < 4; ++r)
                C[(size_t)(bm + wm + i*16 + crow0 + r) * 1536 + bn + wn + j*16 + ccol] = acc[i][j][r];
}

// ---- 3) featurize: Cp cols [0,256)=Q,[256,512)=K -> Qf,Kf bf16 [bh][t][DP] ----
__global__ __launch_bounds__(256)
void featurize(const float* __restrict__ Cp,
               short* __restrict__ Qf, short* __restrict__ Kf) {
    const int bt = blockIdx.x;
    const int b = bt >> 9, t = bt & 511;
    const int tid = threadIdx.x;
    __shared__ float sq[256], sk[256];
    __shared__ unsigned short sfq[2560], sfk[2560];   // [h*160 + D]
    sq[tid] = Cp[(size_t)bt * 1536 + tid];
    sk[tid] = Cp[(size_t)bt * 1536 + 256 + tid];
    __syncthreads();
    const int h = tid >> 4, sl = tid & 15;
    const float* q = sq + h * 16;
    const float* k = sk + h * 16;
    #pragma unroll
    for (int m = 0; m < 10; ++m) {
        const int D = sl * 10 + m;
        float fq, fk;
        if (D == 0)        { fq = 1.f; fk = 1.f; }
        else if (D < 17)   { fq = q[D-1] * 0.5f; fk = k[D-1] * 0.5f; }
        else if (D < 33)   { float a = q[D-17], c = k[D-17];
                             fq = a * a * 0.17677669529663687f;
                             fk = c * c * 0.17677669529663687f; }
        else if (D < 153)  { int p = D - 33; int ii = c_iu[p], jj = c_ju[p];
                             fq = q[ii] * q[jj] * 0.25f;
                             fk = k[ii] * k[jj] * 0.25f; }
        else               { fq = 0.f; fk = 0.f; }
        sfq[h*160 + D] = f2bf_rne(fq);
        sfk[h*160 + D] = f2bf_rne(fk);
    }
    __syncthreads();
    // vector dump: 2 tensors x 16 h x 20 chunks of 8 shorts
    for (int e = tid; e < 640; e += 256) {
        const int tensor = (e >= 320) ? 1 : 0;
        const int i = e - tensor * 320;
        const int hh = i / 20, off = (i % 20) * 8;
        bf16x8 v = *(const bf16x8*)((tensor ? sfk : sfq) + hh*160 + off);
        short* dst = (tensor ? Kf : Qf) + ((size_t)(b*NH + hh)*T + t) * DP + off;
        *(bf16x8*)dst = v;
    }
}

// ---- 4) chunk_state: S[d][D] = sum_t V[t][d]*Kf[t][D]; z[D] ----
__global__ __launch_bounds__(256)
void chunk_state(const short* __restrict__ Kf, const float* __restrict__ Cp,
                 float* __restrict__ S, float* __restrict__ Z) {
    const int bh = blockIdx.x >> 3, c = blockIdx.x & 7;
    const int b = bh >> 4, h = bh & 15;
    const int tid = threadIdx.x;
    const int lane = tid & 63, w = tid >> 6;
    const int wm = (w & 1) * 32, wn = (w >> 1) * 80;
    const int fm = lane & 15, fk = (lane >> 4) * 8;
    __shared__ unsigned short sK[64][164];   // [t][D], stride chosen for frag-read banking
    __shared__ unsigned short sV[64][68];    // [t][d]
    const int r = tid >> 2, q4 = tid & 3;
    // stage Kf row (straight bf16 copy, b64 LDS writes)
    {
        const short* kp = Kf + ((size_t)bh*T + c*CH + r) * DP + q4*40;
        #pragma unroll
        for (int bx = 0; bx < 5; ++bx) {
            union { bf16x8 v; short4v h2[2]; } u;
            u.v = *(const bf16x8*)(kp + bx*8);
            *(short4v*)&sK[r][q4*40 + bx*8]     = u.h2[0];
            *(short4v*)&sK[r][q4*40 + bx*8 + 4] = u.h2[1];
        }
    }
    // stage V tile (fp32 -> bf16), [t][d]
    {
        const float* vsrc = Cp + (size_t)(b*T + c*CH + r) * 1536 + 512 + h*HD + q4*16;
        float vf[16];
        *(float4*)&vf[0]  = *(const float4*)(vsrc + 0);
        *(float4*)&vf[4]  = *(const float4*)(vsrc + 4);
        *(float4*)&vf[8]  = *(const float4*)(vsrc + 8);
        *(float4*)&vf[12] = *(const float4*)(vsrc + 12);
        #pragma unroll
        for (int p = 0; p < 4; ++p) {
            short4v s;
            #pragma unroll
            for (int e = 0; e < 4; ++e) s[e] = (short)f2bf_rne(vf[p*4 + e]);
            *(short4v*)&sV[r][q4*16 + p*4] = s;
        }
    }
    __syncthreads();
    // z[D]
    if (tid < DP) {
        float zz = 0.f;
        for (int tt = 0; tt < CH; ++tt) zz += bf2f(sK[tt][tid]);
        Z[((size_t)(bh*NC + c)) * DP + tid] = zz;
    }
    // S via MFMA with transposed gathers
    f32x4 acc[2][5] = {};
    #pragma unroll
    for (int k0 = 0; k0 < 64; k0 += 32) {
        bf16x8 a[2];
        #pragma unroll
        for (int i = 0; i < 2; ++i) {
            union { bf16x8 v; unsigned short u[8]; } g;
            #pragma unroll
            for (int e = 0; e < 8; ++e) g.u[e] = sV[k0 + fk + e][wm + i*16 + fm];
            a[i] = g.v;
        }
        #pragma unroll
        for (int j = 0; j < 5; ++j) {
            union { bf16x8 v; unsigned short u[8]; } g;
            #pragma unroll
            for (int e = 0; e < 8; ++e) g.u[e] = sK[k0 + fk + e][wn + j*16 + fm];
            #pragma unroll
            for (int i = 0; i < 2; ++i)
                acc[i][j] = mfma1(a[i], g.v, acc[i][j]);
        }
    }
    const int crow0 = (lane >> 4) * 4, ccol = lane & 15;
    float* Sb = S + ((size_t)(bh*NC + c)) * CH * DP;
    #pragma unroll
    for (int i = 0; i < 2; ++i)
        #pragma unroll
        for (int j = 0; j < 5; ++j)
            #pragma unroll
            for (int rr = 0; rr < 4; ++rr)
                Sb[(size_t)(wm + i*16 + crow0 + rr) * DP + wn + j*16 + ccol] = acc[i][j][rr];
}

// ---- 5) chunk_out: y = Qf@P^T + tril(Qf@Kf^T)@V, /den; Y bf16 [bt][1024] ----
__global__ __launch_bounds__(256)
void chunk_out(const short* __restrict__ Qf, const short* __restrict__ Kf,
               const float* __restrict__ Cp,
               const float* __restrict__ S, const float* __restrict__ Z,
               short* __restrict__ Y) {
    const int bh = blockIdx.x >> 3, c = blockIdx.x & 7;
    const int b = bh >> 4, h = bh & 15;
    const int tid = threadIdx.x;
    const int lane = tid & 63, w = tid >> 6;
    const int wm = (w & 1) * 32, wn = (w >> 1) * 32;
    const int fm = lane & 15, fk = (lane >> 4) * 8;
    __shared__ float sP[64][164];
    __shared__ float sA[64][68];
    __shared__ unsigned short sV[64][68];   // [t][d]
    __shared__ float sZ[DP];
    __shared__ float sDen[64];
    const int r = tid >> 2, q4 = tid & 3;
    // stage V tile (needed for intra AV), [t][d] bf16
    {
        const float* vsrc = Cp + (size_t)(b*T + c*CH + r) * 1536 + 512 + h*HD + q4*16;
        float vf[16];
        *(float4*)&vf[0]  = *(const float4*)(vsrc + 0);
        *(float4*)&vf[4]  = *(const float4*)(vsrc + 4);
        *(float4*)&vf[8]  = *(const float4*)(vsrc + 8);
        *(float4*)&vf[12] = *(const float4*)(vsrc + 12);
        #pragma unroll
        for (int p = 0; p < 4; ++p) {
            short4v s;
            #pragma unroll
            for (int e = 0; e < 4; ++e) s[e] = (short)f2bf_rne(vf[p*4 + e]);
            *(short4v*)&sV[r][q4*16 + p*4] = s;
        }
    }
    // prefix sums of S, Z over chunks < c
    for (int e = tid; e < 2560; e += 256) {
        const int d = e / 40, D4 = (e % 40) * 4;
        float4 a = make_float4(0.f, 0.f, 0.f, 0.f);
        for (int cc = 0; cc < c; ++cc) {
            float4 s = *(const float4*)(S + (((size_t)(bh*NC + cc)) * CH + d) * DP + D4);
            a.x += s.x; a.y += s.y; a.z += s.z; a.w += s.w;
        }
        *(float4*)&sP[d][D4] = a;
    }
    if (tid < DP) {
        float zz = 0.f;
        for (int cc = 0; cc < c; ++cc) zz += Z[((size_t)(bh*NC + cc)) * DP + tid];
        sZ[tid] = zz;
    }
    __syncthreads();
    // main K-loop over feature dim
    f32x4 accA[2][2] = {};
    f32x4 accI[2][2] = {};
    const size_t qkbase = ((size_t)bh*T + c*CH);
    for (int k0 = 0; k0 < DP; k0 += 32) {
        bf16x8 qv[2];
        #pragma unroll
        for (int i = 0; i < 2; ++i)
            qv[i] = *(const bf16x8*)(Qf + (qkbase + wm + i*16 + fm) * DP + k0 + fk);
        #pragma unroll
        for (int j = 0; j < 2; ++j) {
            bf16x8 kv = *(const bf16x8*)(Kf + (qkbase + wn + j*16 + fm) * DP + k0 + fk);
            float pf[8];
            *(float4*)&pf[0] = *(const float4*)&sP[wn + j*16 + fm][k0 + fk];
            *(float4*)&pf[4] = *(const float4*)&sP[wn + j*16 + fm][k0 + fk + 4];
            bf16x8 pv = pack8(pf);
            #pragma unroll
            for (int i = 0; i < 2; ++i) {
                accA[i][j] = mfma1(qv[i], kv, accA[i][j]);
                accI[i][j] = mfma1(qv[i], pv, accI[i][j]);
            }
        }
    }
    // den_inter
    {
        const int t_ = tid >> 2;
        const short* qp = Qf + (qkbase + t_) * DP + q4*40;
        float dp = 0.f;
        #pragma unroll
        for (int bx = 0; bx < 5; ++bx) {
            bf16x8 v = *(const bf16x8*)(qp + bx*8);
            #pragma unroll
            for (int e = 0; e < 8; ++e)
                dp += bf2f((unsigned short)v[e]) * sZ[q4*40 + bx*8 + e];
        }
        dp += __shfl_xor(dp, 1);
        dp += __shfl_xor(dp, 2);
        if (q4 == 0) sDen[t_] = dp;
    }
    // masked A -> LDS
    {
        const int crow0 = (lane >> 4) * 4, ccol = lane & 15;
        #pragma unroll
        for (int i = 0; i < 2; ++i)
            #pragma unroll
            for (int j = 0; j < 2; ++j)
                #pragma unroll
                for (int rr = 0; rr < 4; ++rr) {
                    const int t_ = wm + i*16 + crow0 + rr, s_ = wn + j*16 + ccol;
                    sA[t_][s_] = (s_ <= t_) ? accA[i][j][rr] : 0.f;
                }
    }
    __syncthreads();
    if (tid < 64) {
        float rs = 0.f;
        for (int s_ = 0; s_ < CH; ++s_) rs += sA[tid][s_];
        sDen[tid] += rs;
    }
    __syncthreads();
    // intra: y += A @ V  (A from sA fp32->bf16; V transposed gather from sV)
    #pragma unroll
    for (int k0 = 0; k0 < 64; k0 += 32) {
        bf16x8 a[2];
        #pragma unroll
        for (int i = 0; i < 2; ++i) {
            float af[8];
            *(float4*)&af[0] = *(const float4*)&sA[wm + i*16 + fm][k0 + fk];
            *(float4*)&af[4] = *(const float4*)&sA[wm + i*16 + fm][k0 + fk + 4];
            a[i] = pack8(af);
        }
        #pragma unroll
        for (int j = 0; j < 2; ++j) {
            union { bf16x8 v; unsigned short u[8]; } g;
            #pragma unroll
            for (int e = 0; e < 8; ++e) g.u[e] = sV[k0 + fk + e][wn + j*16 + fm];
            #pragma unroll
            for (int i = 0; i < 2; ++i)
                accI[i][j] = mfma1(a[i], g.v, accI[i][j]);
        }
    }
    // epilogue: y/den -> bf16 -> Y
    {
        const int crow0 = (lane >> 4) * 4, ccol = lane & 15;
        #pragma unroll
        for (int i = 0; i < 2; ++i)
            #pragma unroll
            for (int rr = 0; rr < 4; ++rr) {
                const int t_ = wm + i*16 + crow0 + rr;
                const float inv = 1.f / (sDen[t_] + 1e-12f);
                const size_t grow = (size_t)(b*T + c*CH + t_) * 1024 + h*HD;
                #pragma unroll
                for (int j = 0; j < 2; ++j)
                    Y[grow + wn + j*16 + ccol] = (short)f2bf_rne(accI[i][j][rr] * inv);
            }
    }
}

// ---- 6) out GEMM: out = Y @ Wo^T; A single bf16, B split (2 MFMAs) ----
__global__ __launch_bounds__(256)
void gemm_out(const short* __restrict__ A, const short* __restrict__ Bh,
              const short* __restrict__ Bl, float* __restrict__ C) {
    __shared__ short sA[64][40], sBh[64][40], sBl[64][40];
    const int tid = threadIdx.x;
    const int bm = blockIdx.y * 64, bn = blockIdx.x * 64;
    const int lane = tid & 63, w = tid >> 6;
    const int wm = (w & 1) * 32, wn = (w >> 1) * 32;
    const int srow = tid >> 2, skq = (tid & 3) * 8;
    const int fm = lane & 15, fk = (lane >> 4) * 8;
    f32x4 acc[2][2] = {};
    const short* pA  = A  + (size_t)(bm + srow) * 1024 + skq;
    const short* pBh = Bh + (size_t)(bn + srow) * 1024 + skq;
    const short* pBl = Bl + (size_t)(bn + srow) * 1024 + skq;
    for (int k0 = 0; k0 < 1024; k0 += 32) {
        bf16x8 va  = *(const bf16x8*)(pA  + k0);
        bf16x8 vbh = *(const bf16x8*)(pBh + k0);
        bf16x8 vbl = *(const bf16x8*)(pBl + k0);
        __syncthreads();
        *(bf16x8*)&sA[srow][skq]  = va;
        *(bf16x8*)&sBh[srow][skq] = vbh;
        *(bf16x8*)&sBl[srow][skq] = vbl;
        __syncthreads();
        bf16x8 a[2], bh[2], bl[2];
        #pragma unroll
        for (int i = 0; i < 2; ++i) {
            a[i]  = *(const bf16x8*)&sA[wm + i*16 + fm][fk];
            bh[i] = *(const bf16x8*)&sBh[wn + i*16 + fm][fk];
            bl[i] = *(const bf16x8*)&sBl[wn + i*16 + fm][fk];
        }
        #pragma unroll
        for (int i = 0; i < 2; ++i)
            #pragma unroll
            for (int j = 0; j < 2; ++j) {
                acc[i][j] = __builtin_amdgcn_mfma_f32_16x16x32_bf16(a[i], bh[j], acc[i][j], 0, 0, 0);
                acc[i][j] = __builtin_amdgcn_mfma_f32_16x16x32_bf16(a[i], bl[j], acc[i][j], 0, 0, 0);
            }
    }
    const int crow0 = (lane >> 4) * 4, ccol = lane & 15;
    #pragma unroll
    for (int i = 0; i < 2; ++i)
        #pragma unroll
        for (int j = 0; j < 2; ++j)
            #pragma unroll
            for (int r = 0; r < 4; ++r)
                C[(size_t)(bm + wm + i*16 + crow0 + r) * 1024 + bn + wn + j*16 + ccol] = acc[i][j][r];
}

extern "C" void kernel_launch(void* const* d_in, const int* in_sizes, int n_in,
                              void* d_out, int out_size, void* d_ws, size_t ws_size,
                              hipStream_t stream) {
    const float* hs = (const float*)d_in[0];
    const float* Wq = (const float*)d_in[1];
    const float* Wk = (const float*)d_in[2];
    const float* Wv = (const float*)d_in[3];
    const float* Wo = (const float*)d_in[4];
    float* out = (float*)d_out;

    char* p = (char*)d_ws;
    float* Cp  = (float*)p; p += (size_t)1024*1536*4;
    short* hsh = (short*)p; p += (size_t)1048576*2;
    short* hsl = (short*)p; p += (size_t)1048576*2;
    short* Wch = (short*)p; p += (size_t)1536*1024*2;
    short* Wcl = (short*)p; p += (size_t)1536*1024*2;
    short* Woh = (short*)p; p += (size_t)1048576*2;
    short* Wol = (short*)p; p += (size_t)1048576*2;
    short* Qf  = (short*)p; p += (size_t)32*T*DP*2;
    short* Kf  = (short*)p; p += (size_t)32*T*DP*2;
    float* S   = (float*)p; p += (size_t)32*NC*CH*DP*4;
    float* Z   = (float*)p; p += (size_t)32*NC*DP*4;
    short* Y   = (short*)p; p += (size_t)1048576*2;

    dim3 blk(256);
    preconv<<<dim3(3584), blk, 0, stream>>>(hs, Wq, Wk, Wv, Wo, hsh, hsl, Wch, Wcl, Woh, Wol);
    gemm_proj<<<dim3(16, 16), blk, 0, stream>>>(hsh, hsl, Wch, Wcl, Cp);
    featurize<<<dim3(1024), blk, 0, stream>>>(Cp, Qf, Kf);
    chunk_state<<<dim3(256), blk, 0, stream>>>(Kf, Cp, S, Z);
    chunk_out<<<dim3(256), blk, 0, stream>>>(Qf, Kf, Cp, S, Z, Y);
    gemm_out<<<dim3(16, 16), blk, 0, stream>>>(Y, Woh, Wol, out);
}